// Round 1
// 403.333 us; speedup vs baseline: 1.0035x; 1.0035x over previous
//
#include <hip/hip_runtime.h>

// Problem constants (fixed by setup_inputs): B=8, C=19, H=512, W=1024
#define NCLASS 19
#define NCNT   (3 * NCLASS)      // 57 counters: pred[19] | true[19] | inter[19]
#define HW (512 * 1024)          // 2^19 pixels per (b, c) plane
#define NB 8
#define NPIX (NB * HW)           // 4,194,304 pixels
#define NGROUP (NPIX / 4)        // 1,048,576 float4 groups
#define GPB 256                  // float4 groups per block -> 1024 px/block
#define GRID (NGROUP / GPB)      // 4096 blocks (16 per CU)
#define NREP 16                  // accumulator replicas (contention spread)

typedef float v4f __attribute__((ext_vector_type(4)));
typedef int   v4i __attribute__((ext_vector_type(4)));

// ws layout: acc[NREP][NCNT] u32 = 3648 B. Zeroed by iou_zero_kernel each
// iteration (ws is poisoned by the harness between iterations).

__global__ __launch_bounds__(1024) void iou_zero_kernel(unsigned int* __restrict__ acc)
{
    const int t = threadIdx.x;
    if (t < NREP * NCNT) acc[t] = 0u;
}

// One float4 group (4 px) per thread. All 19 class vectors are loaded into a
// compile-time-indexed array BEFORE the argmax loop: 19 independent dwordx4
// loads in flight per thread (19 KB per wave), ~100 VGPRs -> 4 waves/SIMD.
// launch_bounds(256,4): cap VGPR at 128 so occupancy holds.
__global__ __launch_bounds__(256, 4) void iou_count_kernel(
    const float* __restrict__ preds,
    const int* __restrict__ targets,
    unsigned int* __restrict__ acc)
{
    __shared__ unsigned int s_cnt[NCNT];   // pred | true | inter

    const int t = threadIdx.x;
    if (t < NCNT) s_cnt[t] = 0u;
    __syncthreads();

    // Block spans 256 consecutive float4 groups = 1024 px; HW/1024 = 512
    // blocks per (b) plane, so every block sits inside one batch plane and
    // every wave load is a contiguous 1 KB dwordx4 access.
    const int g  = blockIdx.x * GPB + t;     // global float4-group id
    const int p0 = g << 2;                   // first pixel of this thread
    const int b  = p0 >> 19;                 // HW == 2^19
    const int hw = p0 & (HW - 1);
    const size_t plane4 = HW / 4;            // plane stride in float4 units

    const v4f* __restrict__ base =
        (const v4f*)(preds + (size_t)b * NCLASS * HW) + (hw >> 2);

    // Phase 1: issue all 19 loads (no consumer in between).
    v4f v[NCLASS];
    #pragma unroll
    for (int c = 0; c < NCLASS; ++c)
        v[c] = __builtin_nontemporal_load(&base[(size_t)c * plane4]);

    // Phase 2: argmax over classes (strict > keeps first max, matching
    // jnp.argmax; softmax is monotonic so argmax(logits) == argmax(probs)).
    v4f m = v[0];
    int ix = 0, iy = 0, iz = 0, iw = 0;
    #pragma unroll
    for (int c = 1; c < NCLASS; ++c) {
        if (v[c].x > m.x) { m.x = v[c].x; ix = c; }
        if (v[c].y > m.y) { m.y = v[c].y; iy = c; }
        if (v[c].z > m.z) { m.z = v[c].z; iz = c; }
        if (v[c].w > m.w) { m.w = v[c].w; iw = c; }
    }

    const v4i ta = __builtin_nontemporal_load(&((const v4i*)targets)[g]);

    atomicAdd(&s_cnt[ix], 1u);
    atomicAdd(&s_cnt[iy], 1u);
    atomicAdd(&s_cnt[iz], 1u);
    atomicAdd(&s_cnt[iw], 1u);

    atomicAdd(&s_cnt[NCLASS + ta.x], 1u);
    atomicAdd(&s_cnt[NCLASS + ta.y], 1u);
    atomicAdd(&s_cnt[NCLASS + ta.z], 1u);
    atomicAdd(&s_cnt[NCLASS + ta.w], 1u);

    if (ix == ta.x) atomicAdd(&s_cnt[2 * NCLASS + ix], 1u);
    if (iy == ta.y) atomicAdd(&s_cnt[2 * NCLASS + iy], 1u);
    if (iz == ta.z) atomicAdd(&s_cnt[2 * NCLASS + iz], 1u);
    if (iw == ta.w) atomicAdd(&s_cnt[2 * NCLASS + iw], 1u);

    __syncthreads();
    // One global-atomic instruction per block (57 lanes, distinct addresses).
    // 16 replicas -> only 256 blocks contend per address. Device-scope by
    // default (G12), so cross-XCD correctness holds.
    if (t < NCNT) atomicAdd(&acc[(blockIdx.x & (NREP - 1)) * NCNT + t], s_cnt[t]);
}

__global__ __launch_bounds__(64) void iou_finalize_kernel(
    const unsigned int* __restrict__ acc,
    float* __restrict__ out)
{
    __shared__ float s_iou[NCLASS];
    const int t = threadIdx.x;

    if (t < NCNT) {
        // fold the 16 replicas (3.6 KB total, L2-resident)
        unsigned int s = 0;
        #pragma unroll
        for (int r = 0; r < NREP; ++r) s += acc[r * NCNT + t];
        // stash totals back in acc[t] via shared-free path: reuse registers
        // through LDS below
        ((unsigned int*)s_iou)[0]; // no-op; totals passed via shared writes below
        __shared__ unsigned int s_tot[NCNT];
        s_tot[t] = s;
        __syncthreads();
        if (t < NCLASS) {
            const unsigned int pc = s_tot[t];
            const unsigned int tc = s_tot[NCLASS + t];
            const unsigned int ic = s_tot[2 * NCLASS + t];
            unsigned int un = pc + tc - ic;
            un = un > 1u ? un : 1u;                  // max(union, 1)
            const float iou = (tc > 0u) ? ((float)ic / (float)un) : 0.0f;
            s_iou[t] = iou;
            if (t >= 1) out[t - 1] = iou;            // iou = iou_all[1:]
        }
    } else {
        __syncthreads();
    }
    __syncthreads();
    if (t == 0) {
        float s = 0.0f;
        for (int c = 1; c < NCLASS; ++c) s += s_iou[c];
        out[NCLASS - 1] = s / (float)(NCLASS - 1);   // mean_iou at out[18]
    }
}

extern "C" void kernel_launch(void* const* d_in, const int* in_sizes, int n_in,
                              void* d_out, int out_size, void* d_ws, size_t ws_size,
                              hipStream_t stream) {
    const float* preds  = (const float*)d_in[0];
    const int* targets  = (const int*)d_in[1];
    float* out          = (float*)d_out;
    unsigned int* acc   = (unsigned int*)d_ws;   // NREP*NCNT*4 = 3648 B

    iou_zero_kernel<<<1, 1024, 0, stream>>>(acc);
    iou_count_kernel<<<GRID, 256, 0, stream>>>(preds, targets, acc);
    iou_finalize_kernel<<<1, 64, 0, stream>>>(acc, out);
}